// Round 10
// baseline (172.596 us; speedup 1.0000x reference)
//
#include <hip/hip_runtime.h>
#include <hip/hip_bf16.h>
#include <math.h>

typedef short short8 __attribute__((ext_vector_type(8)));
typedef short short4v __attribute__((ext_vector_type(4)));
typedef float f32x4 __attribute__((ext_vector_type(4)));

__device__ __forceinline__ short f2bf(float f) {
  union { float f; unsigned u; } v; v.f = f;
  unsigned r = v.u + 0x7FFFu + ((v.u >> 16) & 1u);
  return (short)(r >> 16);
}
__device__ __forceinline__ float bf2f(short s) {
  union { unsigned u; float f; } v; v.u = ((unsigned)(unsigned short)s) << 16;
  return v.f;
}
__device__ __forceinline__ unsigned cvtpk(float lo, float hi) {
  unsigned r;
  asm("v_cvt_pk_bf16_f32 %0, %1, %2" : "=v"(r) : "v"(lo), "v"(hi));
  return r;
}

// -------- generic f32 -> bf16 cast, 4 elems/thread -----------------------
__global__ __launch_bounds__(256) void cast_kernel(const float* __restrict__ in,
                                                   short* __restrict__ out, int n4) {
  int i = blockIdx.x * blockDim.x + threadIdx.x;
  if (i < n4) {
    float4 v = ((const float4*)in)[i];
    short4v o;
    o.x = f2bf(v.x); o.y = f2bf(v.y); o.z = f2bf(v.z); o.w = f2bf(v.w);
    ((short4v*)out)[i] = o;
  }
}

// -------- w1 prep: bf16 cast + row sums w1s[o] = sum_c w1[o,c] ------------
__global__ __launch_bounds__(256) void w1_prep(const float* __restrict__ w1,
                                               short* __restrict__ w1_bf,
                                               float* __restrict__ w1s) {
  int t = blockIdx.x * 256 + threadIdx.x;   // 4096 threads
  int o = t >> 2, qt = t & 3;
  const float* src = w1 + (size_t)o * 512 + qt * 128;
  short* dst = w1_bf + (size_t)o * 512 + qt * 128;
  float s = 0.f;
#pragma unroll
  for (int i = 0; i < 128; i += 4) {
    float4 v = *(const float4*)(src + i);
    s += v.x + v.y + v.z + v.w;
    short4v ov; ov.x = f2bf(v.x); ov.y = f2bf(v.y); ov.z = f2bf(v.z); ov.w = f2bf(v.w);
    *(short4v*)(dst + i) = ov;
  }
  __shared__ float red[256];
  red[threadIdx.x] = s;
  __syncthreads();
  if (qt == 0) {
    int tx = threadIdx.x;
    w1s[o] = red[tx] + red[tx + 1] + red[tx + 2] + red[tx + 3];
  }
}

// -------- DCT even/odd prep: e[n]=x[n]+x[1023-n], o[n]=x[n]-x[1023-n] -----
__global__ __launch_bounds__(256) void prep_eo(const float* __restrict__ x,
                                               short* __restrict__ eo) {
  int t = blockIdx.x * 256 + threadIdx.x;     // 16384 * 128
  int bc = t >> 7, n0 = (t & 127) * 4;        // n0 in [0,512)
  const float* xr = x + (size_t)bc * 1024;
  float4 f = *(const float4*)(xr + n0);
  float4 r = *(const float4*)(xr + 1020 - n0);
  short4v ef, of;
  ef.x = f2bf(f.x + r.w); ef.y = f2bf(f.y + r.z); ef.z = f2bf(f.z + r.y); ef.w = f2bf(f.w + r.x);
  of.x = f2bf(f.x - r.w); of.y = f2bf(f.y - r.z); of.z = f2bf(f.z - r.y); of.w = f2bf(f.w - r.x);
  *(short4v*)&eo[(size_t)bc * 512 + n0] = ef;
  *(short4v*)&eo[8388608 + (size_t)bc * 512 + n0] = of;
}

// -------- Deo[parity][k'][n] = 2*cos(pi/2048 * (2k'+parity) * (2n+1)) -----
__global__ __launch_bounds__(256) void build_Deo(short* __restrict__ D) {
  int t = blockIdx.x * 256 + threadIdx.x;     // 2*512*512 = 524288
  int parity = t >> 18, rem = t & 262143;
  int k2 = rem >> 9, n = rem & 511;
  const float s = 1.5339807878856412e-03f;    // pi/2048
  float arg = (s * (float)(2 * k2 + parity)) * (float)(2 * n + 1);
  D[t] = f2bf(2.0f * cosf(arg));
}

// -------- fold 8 row-block partials -> per-(b,c) mu, rstd -----------------
__global__ __launch_bounds__(256) void ln_stats(const float2* __restrict__ partial,
                                                float2* __restrict__ musd) {
  int n = blockIdx.x * 256 + threadIdx.x;   // 16384
  float S = 0.f, Q = 0.f;
#pragma unroll
  for (int r = 0; r < 8; ++r) {
    float2 p = partial[(size_t)r * 16384 + n];
    S += p.x; Q += p.y;
  }
  float mu  = S * (1.f / 1024.f);
  float var = Q * (1.f / 1024.f) - mu * mu;   // biased, like nn.LayerNorm
  float2 o; o.x = mu; o.y = rsqrtf(var + 1e-6f);
  musd[n] = o;
}

// ======== 128x128 dbuf BT-GEMM, 4 waves, 2 blocks/CU: C = A·B^T ===========
// (unchanged from round 9 — see comments there)
// EPI 0: DCT halves, bz=parity, output row=2r+bz, LN partials slot bz*4+bx.
// EPI 2: out = x * sigmoid(C), fp32 x.
template<int EPI>
__global__ __launch_bounds__(256, 2) void gemm128(
    const short* __restrict__ A, const short* __restrict__ B,
    void* __restrict__ Cout, const float* __restrict__ X,
    float2* __restrict__ P, int K, int NT, long strideA, long strideB)
{
  __shared__ short As[2][8192];
  __shared__ short Bs[2][8192];
  const int tid = threadIdx.x;     // 256
  const int l   = tid & 63;
  const int w   = tid >> 6;        // wave 0..3
  const int wm  = w >> 1;          // 0..1
  const int wc  = w & 1;           // 0..1
  const int l7  = l & 7;
  const int lr  = l & 15;
  const int lhi = l >> 4;

  const int nwg = gridDim.x, q = nwg >> 3, orig = blockIdx.x;
  const int wgid = (orig & 7) * q + (orig >> 3);
  int bx, by, bz;
  if (EPI == 0)      { bx = wgid & 3; bz = (wgid >> 2) & 1; by = wgid >> 3; }
  else               { bx = wgid & 3; by = (wgid >> 2) & 7; bz = wgid >> 5; }

  const long row0 = (long)bx * 128, col0 = (long)by * 128;
  const short* Ab = A + (size_t)bz * strideA + (size_t)row0 * K;
  const short* Bb = B + (size_t)bz * strideB + (size_t)col0 * K;

  const int rowb  = tid >> 3;                       // 0..31
  const int colel = ((tid & 7) ^ ((tid >> 3) & 7)) * 8;
  const int abase = (wm * 64 + lr) * 64;
  const int bbase = (wc * 64 + lr) * 64;
  const int s0 = ((lhi    ) ^ l7) * 8;
  const int s1 = ((lhi + 4) ^ l7) * 8;

  f32x4 acc[4][4];
#pragma unroll
  for (int i = 0; i < 4; ++i)
#pragma unroll
    for (int j = 0; j < 4; ++j) acc[i][j] = (f32x4){0.f, 0.f, 0.f, 0.f};

#define GLL(SRC, DST) __builtin_amdgcn_global_load_lds(                      \
      (const __attribute__((address_space(1))) void*)(SRC),                  \
      (__attribute__((address_space(3))) void*)(DST), 16, 0, 0)

#define STAGE(KT, D) do {                                                    \
    const size_t ko_ = (size_t)(KT) * 64 + colel;                            \
    _Pragma("unroll")                                                        \
    for (int r_ = 0; r_ < 4; ++r_)                                           \
      GLL(Ab + (size_t)(r_ * 32 + rowb) * K + ko_,                           \
          &As[D][(r_ * 32 + rowb) * 64 + (tid & 7) * 8]);                    \
    _Pragma("unroll")                                                        \
    for (int r_ = 0; r_ < 4; ++r_)                                           \
      GLL(Bb + (size_t)(r_ * 32 + rowb) * K + ko_,                           \
          &Bs[D][(r_ * 32 + rowb) * 64 + (tid & 7) * 8]);                    \
  } while (0)

#define LD8(PTR, OFF) (*(const short8*)&(PTR)[OFF])
#define MFMA(AV, BV, C) __builtin_amdgcn_mfma_f32_16x16x32_bf16(AV, BV, C, 0, 0, 0)
#define SBAR __builtin_amdgcn_s_barrier()
#define SCHB __builtin_amdgcn_sched_barrier(0)

#define MFMA16(A0, A1, A2, A3, B0, B1, B2, B3)                               \
    __builtin_amdgcn_s_setprio(1);                                           \
    acc[0][0]=MFMA(A0,B0,acc[0][0]); acc[0][1]=MFMA(A0,B1,acc[0][1]);        \
    acc[0][2]=MFMA(A0,B2,acc[0][2]); acc[0][3]=MFMA(A0,B3,acc[0][3]);        \
    acc[1][0]=MFMA(A1,B0,acc[1][0]); acc[1][1]=MFMA(A1,B1,acc[1][1]);        \
    acc[1][2]=MFMA(A1,B2,acc[1][2]); acc[1][3]=MFMA(A1,B3,acc[1][3]);        \
    acc[2][0]=MFMA(A2,B0,acc[2][0]); acc[2][1]=MFMA(A2,B1,acc[2][1]);        \
    acc[2][2]=MFMA(A2,B2,acc[2][2]); acc[2][3]=MFMA(A2,B3,acc[2][3]);        \
    acc[3][0]=MFMA(A3,B0,acc[3][0]); acc[3][1]=MFMA(A3,B1,acc[3][1]);        \
    acc[3][2]=MFMA(A3,B2,acc[3][2]); acc[3][3]=MFMA(A3,B3,acc[3][3]);        \
    __builtin_amdgcn_s_setprio(0);

  STAGE(0, 0);
  STAGE(1, 1);

  int cur = 0;
  for (int kt = 0; kt < NT; ++kt) {
    if (kt + 1 < NT) { asm volatile("s_waitcnt vmcnt(8)" ::: "memory"); }
    else             { asm volatile("s_waitcnt vmcnt(0)" ::: "memory"); }
    SCHB; SBAR;
    const short* Ad = As[cur];
    const short* Bd = Bs[cur];
    short8 a00, a01, a02, a03, b00, b01, b02, b03;
    short8 a10, a11, a12, a13, b10, b11, b12, b13;
    a00 = LD8(Ad, abase + 0 * 1024 + s0);
    a01 = LD8(Ad, abase + 1 * 1024 + s0);
    a02 = LD8(Ad, abase + 2 * 1024 + s0);
    a03 = LD8(Ad, abase + 3 * 1024 + s0);
    b00 = LD8(Bd, bbase + 0 * 1024 + s0);
    b01 = LD8(Bd, bbase + 1 * 1024 + s0);
    b02 = LD8(Bd, bbase + 2 * 1024 + s0);
    b03 = LD8(Bd, bbase + 3 * 1024 + s0);
    a10 = LD8(Ad, abase + 0 * 1024 + s1);
    a11 = LD8(Ad, abase + 1 * 1024 + s1);
    a12 = LD8(Ad, abase + 2 * 1024 + s1);
    a13 = LD8(Ad, abase + 3 * 1024 + s1);
    b10 = LD8(Bd, bbase + 0 * 1024 + s1);
    b11 = LD8(Bd, bbase + 1 * 1024 + s1);
    b12 = LD8(Bd, bbase + 2 * 1024 + s1);
    b13 = LD8(Bd, bbase + 3 * 1024 + s1);
    SCHB;
    asm volatile("s_waitcnt lgkmcnt(8)" ::: "memory");
    SCHB;
    MFMA16(a00, a01, a02, a03, b00, b01, b02, b03)
    SCHB;
    asm volatile("s_waitcnt lgkmcnt(0)" ::: "memory");
    SCHB; SBAR;
    if (kt + 2 < NT) STAGE(kt + 2, cur);
    SCHB;
    MFMA16(a10, a11, a12, a13, b10, b11, b12, b13)
    SCHB;
    cur ^= 1;
  }

  // ---------------- epilogue ----------------
  float sv[4], qv[4];
#pragma unroll
  for (int ni = 0; ni < 4; ++ni) { sv[ni] = 0.f; qv[ni] = 0.f; }

#pragma unroll
  for (int mi = 0; mi < 4; ++mi) {
#pragma unroll
    for (int ni = 0; ni < 4; ++ni) {
#pragma unroll
      for (int j = 0; j < 4; ++j) {
        int r  = (int)row0 + wm * 64 + mi * 16 + lhi * 4 + j;
        int cc = (int)col0 + wc * 64 + ni * 16 + lr;
        float v = acc[mi][ni][j];
        if (EPI == 0) {
          sv[ni] += v; qv[ni] += v * v;
          int rr = r * 2 + bz;     // interleave even/odd k-rows
          ((short*)Cout)[((size_t)(cc >> 9) << 19) + (size_t)rr * 512 + (cc & 511)] = f2bf(v);
        } else {
          size_t idx = (size_t)bz * 524288 + (size_t)r * 1024 + cc;
          float g = 1.f / (1.f + __expf(-v));
          ((float*)Cout)[idx] = X[idx] * g;
        }
      }
    }
  }

  if (EPI == 0) {
    __syncthreads();
    float* redS = (float*)&As[0][0];       // [128 cols][8 contributors]
    float* redQ = redS + 1024;
    const int contrib = wm * 4 + lhi;
#pragma unroll
    for (int ni = 0; ni < 4; ++ni) {
      int ccl = wc * 64 + ni * 16 + lr;
      redS[ccl * 8 + contrib] = sv[ni];
      redQ[ccl * 8 + contrib] = qv[ni];
    }
    __syncthreads();
    if (tid < 128) {
      float S = 0.f, Q = 0.f;
#pragma unroll
      for (int i = 0; i < 8; ++i) { S += redS[tid * 8 + i]; Q += redQ[tid * 8 + i]; }
      float2 o; o.x = S; o.y = Q;
      P[(size_t)(bz * 4 + bx) * 16384 + col0 + tid] = o;
    }
  }
#undef MFMA16
#undef STAGE
}

// ======== GEMM2 with fused LayerNorm (A = raw freqT, reg-staged) ==========
// z1t[b][p][o] = relu(lnw[p]*C + lnb[p]*w1s[o]),  C = sum_c (v-mu_c)*rstd_c
// * w1[o,c].  A staged global->reg->(per-c affine)->ds_write (XOR layout);
// B (w1) via global_load_lds.  Per iter: top SBAR; 16 ds_read; vmcnt(0);
// transform+4 ds_write (next tile A); lgkm(12); MFMA k0; lgkm(4); SBAR;
// issue {4 B-GLL, 4 A-loads, 4 musd} for kt+2; MFMA k1; lgkm(0).
__global__ __launch_bounds__(256, 2) void gemm2ln(
    const short* __restrict__ A, const short* __restrict__ B,
    short* __restrict__ Cout, const float2* __restrict__ musd,
    const float* __restrict__ lnw, const float* __restrict__ lnb,
    const float* __restrict__ w1s)
{
  const int K = 512, NT = 8;
  __shared__ short As[2][8192];
  __shared__ short Bs[2][8192];
  const int tid = threadIdx.x;
  const int l   = tid & 63;
  const int w   = tid >> 6;
  const int wm  = w >> 1;
  const int wc  = w & 1;
  const int l7  = l & 7;
  const int lr  = l & 15;
  const int lhi = l >> 4;

  const int nwg = gridDim.x, q = nwg >> 3, orig = blockIdx.x;
  const int wgid = (orig & 7) * q + (orig >> 3);
  const int by = wgid & 7, bx = (wgid >> 3) & 7, bz = wgid >> 6;

  const long row0 = (long)bx * 128, col0 = (long)by * 128;
  const short* Ab = A + (size_t)bz * 524288 + (size_t)row0 * K;
  const short* Bb = B + (size_t)col0 * K;
  const float2* msb = musd + bz * 512;

  const int rowb  = tid >> 3;
  const int slot  = tid & 7;
  const int colel = (slot ^ (rowb & 7)) * 8;
  const int abase = (wm * 64 + lr) * 64;
  const int bbase = (wc * 64 + lr) * 64;
  const int s0 = ((lhi    ) ^ l7) * 8;
  const int s1 = ((lhi + 4) ^ l7) * 8;

  f32x4 acc[4][4];
#pragma unroll
  for (int i = 0; i < 4; ++i)
#pragma unroll
    for (int j = 0; j < 4; ++j) acc[i][j] = (f32x4){0.f, 0.f, 0.f, 0.f};

#define SBAR __builtin_amdgcn_s_barrier()
#define SCHB __builtin_amdgcn_sched_barrier(0)
#define LD8(PTR, OFF) (*(const short8*)&(PTR)[OFF])
#define MFMA(AV, BV, C) __builtin_amdgcn_mfma_f32_16x16x32_bf16(AV, BV, C, 0, 0, 0)
#define GLLB(SRC, DST) __builtin_amdgcn_global_load_lds(                     \
      (const __attribute__((address_space(1))) void*)(SRC),                  \
      (__attribute__((address_space(3))) void*)(DST), 16, 0, 0)

  short8 ar0, ar1, ar2, ar3;
  float4 m01, m23, m45, m67;

#define ISSUE(KT, D) do {                                                    \
    const size_t ko_ = (size_t)(KT) * 64 + colel;                            \
    _Pragma("unroll")                                                        \
    for (int r_ = 0; r_ < 4; ++r_)                                           \
      GLLB(Bb + (size_t)(r_ * 32 + rowb) * K + ko_,                          \
           &Bs[D][(r_ * 32 + rowb) * 64 + slot * 8]);                        \
    ar0 = LD8(Ab, (size_t)(0 * 32 + rowb) * K + ko_);                        \
    ar1 = LD8(Ab, (size_t)(1 * 32 + rowb) * K + ko_);                        \
    ar2 = LD8(Ab, (size_t)(2 * 32 + rowb) * K + ko_);                        \
    ar3 = LD8(Ab, (size_t)(3 * 32 + rowb) * K + ko_);                        \
    const float* mp_ = (const float*)&msb[(KT) * 64 + colel];                \
    m01 = *(const float4*)(mp_ + 0);                                         \
    m23 = *(const float4*)(mp_ + 4);                                         \
    m45 = *(const float4*)(mp_ + 8);                                         \
    m67 = *(const float4*)(mp_ + 12);                                        \
  } while (0)

#define XFORM_ONE(AV, DROW, D) do {                                          \
    unsigned u0_ = cvtpk((bf2f(AV[0]) - m01.x) * m01.y,                      \
                         (bf2f(AV[1]) - m01.z) * m01.w);                     \
    unsigned u1_ = cvtpk((bf2f(AV[2]) - m23.x) * m23.y,                      \
                         (bf2f(AV[3]) - m23.z) * m23.w);                     \
    unsigned u2_ = cvtpk((bf2f(AV[4]) - m45.x) * m45.y,                      \
                         (bf2f(AV[5]) - m45.z) * m45.w);                     \
    unsigned u3_ = cvtpk((bf2f(AV[6]) - m67.x) * m67.y,                      \
                         (bf2f(AV[7]) - m67.z) * m67.w);                     \
    int4 wv_; wv_.x = (int)u0_; wv_.y = (int)u1_; wv_.z = (int)u2_; wv_.w = (int)u3_; \
    *(int4*)&As[D][((DROW) * 32 + rowb) * 64 + slot * 8] = wv_;              \
  } while (0)

#define XFORM(D) do {                                                        \
    XFORM_ONE(ar0, 0, D); XFORM_ONE(ar1, 1, D);                              \
    XFORM_ONE(ar2, 2, D); XFORM_ONE(ar3, 3, D);                              \
  } while (0)

  // prologue
  ISSUE(0, 0);
  asm volatile("s_waitcnt vmcnt(0)" ::: "memory");
  SCHB;
  XFORM(0);
  ISSUE(1, 1);
  asm volatile("s_waitcnt lgkmcnt(0)" ::: "memory");
  SCHB;

  int cur = 0;
  for (int kt = 0; kt < NT; ++kt) {
    SBAR;
    const short* Ad = As[cur];
    const short* Bd = Bs[cur];
    short8 a00, a01, a02, a03, b00, b01, b02, b03;
    short8 a10, a11, a12, a13, b10, b11, b12, b13;
    a00 = LD8(Ad, abase + 0 * 1024 + s0);
    a01 = LD8(Ad, abase + 1 * 1024 + s0);
    a02 = LD8(Ad, abase + 2 * 1024 + s0);
    a03 = LD8(Ad, abase + 3 * 1024 + s0);
    b00 = LD8(Bd, bbase + 0 * 1024 + s0);
    b01 = LD8(Bd, bbase + 1 * 1024 + s0);
    b02 = LD8(Bd, bbase + 2 * 1024 + s0);
    b03 = LD8(Bd, bbase + 3 * 1024 + s0);
    a10 = LD8(Ad, abase + 0 * 1024 + s1);
    a11 = LD8(Ad, abase + 1 * 1024 + s1);
    a12 = LD8(Ad, abase + 2 * 1024 + s1);
    a13 = LD8(Ad, abase + 3 * 1024 + s1);
    b10 = LD8(Bd, bbase + 0 * 1024 + s1);
    b11 = LD8(Bd, bbase + 1 * 1024 + s1);
    b12 = LD8(Bd, bbase + 2 * 1024 + s1);
    b13 = LD8(Bd, bbase + 3 * 1024 + s1);
    SCHB;
    if (kt + 1 < NT) {
      asm volatile("s_waitcnt vmcnt(0)" ::: "memory");  // A/musd/B-GLL(kt+1)
      SCHB;
      XFORM(cur ^ 1);                                   // A(kt+1) -> other buf
      SCHB;
      asm volatile("s_waitcnt lgkmcnt(12)" ::: "memory");  // k0 frags ready
    } else {
      asm volatile("s_waitcnt lgkmcnt(8)" ::: "memory");
    }
    SCHB;
    __builtin_amdgcn_s_setprio(1);
    acc[0][0]=MFMA(a00,b00,acc[0][0]); acc[0][1]=MFMA(a00,b01,acc[0][1]);
    acc[0][2]=MFMA(a00,b02,acc[0][2]); acc[0][3]=MFMA(a00,b03,acc[0][3]);
    acc[1][0]=MFMA(a01,b00,acc[1][0]); acc[1][1]=MFMA(a01,b01,acc[1][1]);
    acc[1][2]=MFMA(a01,b02,acc[1][2]); acc[1][3]=MFMA(a01,b03,acc[1][3]);
    acc[2][0]=MFMA(a02,b00,acc[2][0]); acc[2][1]=MFMA(a02,b01,acc[2][1]);
    acc[2][2]=MFMA(a02,b02,acc[2][2]); acc[2][3]=MFMA(a02,b03,acc[2][3]);
    acc[3][0]=MFMA(a03,b00,acc[3][0]); acc[3][1]=MFMA(a03,b01,acc[3][1]);
    acc[3][2]=MFMA(a03,b02,acc[3][2]); acc[3][3]=MFMA(a03,b03,acc[3][3]);
    __builtin_amdgcn_s_setprio(0);
    SCHB;
    if (kt + 1 < NT) { asm volatile("s_waitcnt lgkmcnt(4)" ::: "memory"); }
    else             { asm volatile("s_waitcnt lgkmcnt(0)" ::: "memory"); }
    SCHB; SBAR;
    if (kt + 2 < NT) ISSUE(kt + 2, cur);
    SCHB;
    __builtin_amdgcn_s_setprio(1);
    acc[0][0]=MFMA(a10,b10,acc[0][0]); acc[0][1]=MFMA(a10,b11,acc[0][1]);
    acc[0][2]=MFMA(a10,b12,acc[0][2]); acc[0][3]=MFMA(a10,b13,acc[0][3]);
    acc[1][0]=MFMA(a11,b10,acc[1][0]); acc[1][1]=MFMA(a11,b11,acc[1][1]);
    acc[1][2]=MFMA(a11,b12,acc[1][2]); acc[1][3]=MFMA(a11,b13,acc[1][3]);
    acc[2][0]=MFMA(a12,b10,acc[2][0]); acc[2][1]=MFMA(a12,b11,acc[2][1]);
    acc[2][2]=MFMA(a12,b12,acc[2][2]); acc[2][3]=MFMA(a12,b13,acc[2][3]);
    acc[3][0]=MFMA(a13,b10,acc[3][0]); acc[3][1]=MFMA(a13,b11,acc[3][1]);
    acc[3][2]=MFMA(a13,b12,acc[3][2]); acc[3][3]=MFMA(a13,b13,acc[3][3]);
    __builtin_amdgcn_s_setprio(0);
    SCHB;
    asm volatile("s_waitcnt lgkmcnt(0)" ::: "memory");  // publish A-writes
    SCHB;
    cur ^= 1;
  }

  // epilogue: z1 = relu(lnw[p]*C + lnb[p]*w1s[o]) -> bf16
  const int rb = (int)row0 + wm * 64 + lhi * 4;
  const int cb = (int)col0 + wc * 64 + lr;
#pragma unroll
  for (int mi = 0; mi < 4; ++mi) {
    float4 wv4 = *(const float4*)&lnw[rb + mi * 16];
    float4 bv4 = *(const float4*)&lnb[rb + mi * 16];
#pragma unroll
    for (int ni = 0; ni < 4; ++ni) {
      int cc = cb + ni * 16;
      float ws = w1s[cc];
#pragma unroll
      for (int j = 0; j < 4; ++j) {
        int r = rb + mi * 16 + j;
        float lw = (j == 0) ? wv4.x : (j == 1) ? wv4.y : (j == 2) ? wv4.z : wv4.w;
        float lb = (j == 0) ? bv4.x : (j == 1) ? bv4.y : (j == 2) ? bv4.z : bv4.w;
        float v = lw * acc[mi][ni][j] + lb * ws;
        Cout[(size_t)bz * 1048576 + (size_t)r * 1024 + cc] = f2bf(v > 0.f ? v : 0.f);
      }
    }
  }
#undef XFORM
#undef XFORM_ONE
#undef ISSUE
#undef GLLB
#undef MFMA
#undef LD8
#undef SBAR
#undef SCHB
}

extern "C" void kernel_launch(void* const* d_in, const int* in_sizes, int n_in,
                              void* d_out, int out_size, void* d_ws, size_t ws_size,
                              hipStream_t stream) {
  const float* x    = (const float*)d_in[0];   // [32,512,1024]
  const float* w1   = (const float*)d_in[1];   // [1024,512]
  const float* w2   = (const float*)d_in[2];   // [512,1024]
  const float* ln_w = (const float*)d_in[3];   // [1024]
  const float* ln_b = (const float*)d_in[4];   // [1024]
  float* out = (float*)d_out;

  char* ws = (char*)d_ws;
  short* Deo    = (short*)(ws);                  //  1,048,576 B [2][512][512]
  short* w1_bf  = (short*)(ws + 1048576);        //  1,048,576 B
  short* w2_bf  = (short*)(ws + 2097152);        //  1,048,576 B
  short* freqT  = (short*)(ws + 3145728);        // 33,554,432 B [b][k][c] (raw)
  short* z1t    = (short*)(ws + 36700160);       // 67,108,864 B [b][p][o]
  short* eo     = z1t;                           // e/o alias z1t (dead by GEMM2)
  float2* part  = (float2*)(ws + 103809024);     //  1,048,576 B [8][16384]
  float2* musd  = (float2*)(ws + 104857600);     //    131,072 B [16384]
  float*  w1s   = (float*)(ws + 104988672);      //      4,096 B [1024]
  // total ~105 MB

  prep_eo<<<dim3(8192), dim3(256), 0, stream>>>(x, eo);
  w1_prep<<<dim3(16), dim3(256), 0, stream>>>(w1, w1_bf, w1s);
  cast_kernel<<<dim3(512), dim3(256), 0, stream>>>(w2, w2_bf, 524288 / 4);
  build_Deo<<<dim3(2048), dim3(256), 0, stream>>>(Deo);

  // GEMM1 (even/odd): C[k',(b,c)] = sum_n Deo[p][k',n]*eo[p][(b,c),n]
  // -> freqT rows 2k'+p (RAW, pre-LN), + LN partials. K=512, NT=8.
  gemm128<0><<<dim3(1024), dim3(256), 0, stream>>>(
      Deo, eo, (void*)freqT, nullptr, part, 512, 8, 262144, 8388608);

  // LN stats: fold 8 partials (2 parity x 4 bx) -> (mu, rstd) per (b,c)
  ln_stats<<<dim3(64), dim3(256), 0, stream>>>(part, musd);

  // GEMM2+LN fused: z1t = relu(lnw*((freqT-mu)*rstd @ w1^T) + lnb*w1s)
  gemm2ln<<<dim3(2048), dim3(256), 0, stream>>>(
      freqT, w1_bf, z1t, musd, ln_w, ln_b, w1s);

  // GEMM3: C[o2,p] = sum_j w2[o2,j] * z1t[b][p,j]; out = x * sigmoid(C)
  gemm128<2><<<dim3(1024), dim3(256), 0, stream>>>(
      w2_bf, z1t, (void*)out, x, nullptr, 1024, 16, 0, 1048576);
}

// Round 11
// 170.343 us; speedup vs baseline: 1.0132x; 1.0132x over previous
//
#include <hip/hip_runtime.h>
#include <hip/hip_bf16.h>
#include <math.h>

typedef short short8 __attribute__((ext_vector_type(8)));
typedef short short4v __attribute__((ext_vector_type(4)));
typedef float f32x4 __attribute__((ext_vector_type(4)));

__device__ __forceinline__ short f2bf(float f) {
  union { float f; unsigned u; } v; v.f = f;
  unsigned r = v.u + 0x7FFFu + ((v.u >> 16) & 1u);
  return (short)(r >> 16);
}
__device__ __forceinline__ float bf2f(short s) {
  union { unsigned u; float f; } v; v.u = ((unsigned)(unsigned short)s) << 16;
  return v.f;
}

// -------- generic f32 -> bf16 cast, 4 elems/thread -----------------------
__global__ __launch_bounds__(256) void cast_kernel(const float* __restrict__ in,
                                                   short* __restrict__ out, int n4) {
  int i = blockIdx.x * blockDim.x + threadIdx.x;
  if (i < n4) {
    float4 v = ((const float4*)in)[i];
    short4v o;
    o.x = f2bf(v.x); o.y = f2bf(v.y); o.z = f2bf(v.z); o.w = f2bf(v.w);
    ((short4v*)out)[i] = o;
  }
}

// -------- DCT even/odd prep: e[n]=x[n]+x[1023-n], o[n]=x[n]-x[1023-n] -----
__global__ __launch_bounds__(256) void prep_eo(const float* __restrict__ x,
                                               short* __restrict__ eo) {
  int t = blockIdx.x * 256 + threadIdx.x;     // 16384 * 128
  int bc = t >> 7, n0 = (t & 127) * 4;        // n0 in [0,512)
  const float* xr = x + (size_t)bc * 1024;
  float4 f = *(const float4*)(xr + n0);
  float4 r = *(const float4*)(xr + 1020 - n0);
  short4v ef, of;
  ef.x = f2bf(f.x + r.w); ef.y = f2bf(f.y + r.z); ef.z = f2bf(f.z + r.y); ef.w = f2bf(f.w + r.x);
  of.x = f2bf(f.x - r.w); of.y = f2bf(f.y - r.z); of.z = f2bf(f.z - r.y); of.w = f2bf(f.w - r.x);
  *(short4v*)&eo[(size_t)bc * 512 + n0] = ef;
  *(short4v*)&eo[8388608 + (size_t)bc * 512 + n0] = of;
}

// -------- Deo[parity][k'][n] = 2*cos(pi/2048 * (2k'+parity) * (2n+1)) -----
__global__ __launch_bounds__(256) void build_Deo(short* __restrict__ D) {
  int t = blockIdx.x * 256 + threadIdx.x;     // 2*512*512 = 524288
  int parity = t >> 18, rem = t & 262143;
  int k2 = rem >> 9, n = rem & 511;
  const float s = 1.5339807878856412e-03f;    // pi/2048
  float arg = (s * (float)(2 * k2 + parity)) * (float)(2 * n + 1);
  D[t] = f2bf(2.0f * cosf(arg));
}

// -------- fold 16 row-block partials -> per-(b,c) mu, rstd ----------------
__global__ __launch_bounds__(256) void ln_stats(const float2* __restrict__ partial,
                                                float2* __restrict__ musd) {
  int n = blockIdx.x * 256 + threadIdx.x;   // 16384
  float S = 0.f, Q = 0.f;
#pragma unroll
  for (int r = 0; r < 16; ++r) {
    float2 p = partial[(size_t)r * 16384 + n];
    S += p.x; Q += p.y;
  }
  float mu  = S * (1.f / 1024.f);
  float var = Q * (1.f / 1024.f) - mu * mu;   // biased, like nn.LayerNorm
  float2 o; o.x = mu; o.y = rsqrtf(var + 1e-6f);
  musd[n] = o;
}

// -------- streaming LN apply: freqT[b][k][c] in place, short8/thread ------
__global__ __launch_bounds__(256) void ln_apply(short* __restrict__ freqT,
                                                const float2* __restrict__ musd,
                                                const float* __restrict__ lnw,
                                                const float* __restrict__ lnb) {
  int t = blockIdx.x * 256 + threadIdx.x;
  int c8 = t & 63;
  int k  = (t >> 6) & 1023;
  int b  = t >> 16;
  size_t idx = ((size_t)b << 19) + (size_t)k * 512 + (size_t)c8 * 8;
  short8 v = *(const short8*)&freqT[idx];
  float w  = lnw[k];
  float bb = lnb[k];
  const float2* ms = &musd[b * 512 + c8 * 8];
  short8 o;
#pragma unroll
  for (int j = 0; j < 8; ++j) {
    float f = bf2f(v[j]);
    float2 m = ms[j];
    o[j] = f2bf((f - m.x) * m.y * w + bb);
  }
  *(short8*)&freqT[idx] = o;
}

// ======== (MI*32)x128 dbuf BT-GEMM, 4 waves, 3 blocks/CU: C = A·B^T =======
// MI=2: tile 64x128, acc[2][4], LDS 48KB -> 3 resident blocks/CU (TLP hides
// the drains per m114); MI=4: 128x128 as round 9. BK=64, counted vmcnt/lgkm
// dbuf schedule, 2 barriers/tile, T2 XOR swizzle (inverse-permuted global
// source, XOR'd ds_read), T1 XCD grid swizzle, grids 2048-4096 blocks.
// EPI 0: DCT halves, bz=parity, out row=2r+bz, LN partials slot bz*8+bx.
// EPI 1: relu -> z1t bf16.  EPI 2: out = x * sigmoid(C), fp32 x.
template<int EPI, int MI>
__global__ __launch_bounds__(256, (MI == 2 ? 3 : 2)) void gemmT(
    const short* __restrict__ A, const short* __restrict__ B,
    void* __restrict__ Cout, const float* __restrict__ X,
    float2* __restrict__ P, int K, int NT, long strideA, long strideB)
{
  __shared__ short As[2][MI * 2048];
  __shared__ short Bs[2][8192];
  const int tid = threadIdx.x;     // 256
  const int l   = tid & 63;
  const int w   = tid >> 6;        // wave 0..3
  const int wm  = w >> 1;          // 0..1
  const int wc  = w & 1;           // 0..1
  const int l7  = l & 7;
  const int lr  = l & 15;
  const int lhi = l >> 4;

  // ---- T1 bijective XCD swizzle (grids divisible by 8) ----
  const int nwg = gridDim.x, q = nwg >> 3, orig = blockIdx.x;
  const int wgid = (orig & 7) * q + (orig >> 3);
  int bx, by, bz;
  if (EPI == 0)      { bx = wgid & 7; bz = (wgid >> 3) & 1;  by = wgid >> 4; }
  else if (EPI == 1) { by = wgid & 7; bx = (wgid >> 3) & 15; bz = wgid >> 7; }
  else               { bx = wgid & 7; by = (wgid >> 3) & 7;  bz = wgid >> 6; }

  const long row0 = (long)bx * (MI * 32), col0 = (long)by * 128;
  const short* Ab = A + (size_t)bz * strideA + (size_t)row0 * K;
  const short* Bb = B + (size_t)bz * strideB + (size_t)col0 * K;

  // staging: per round 32 rows; thread -> row (tid>>3), 16B slot (tid&7);
  // global col inverse-swizzled so linear GLL dest realizes XOR layout.
  const int rowb  = tid >> 3;                       // 0..31
  const int slot  = tid & 7;
  const int colel = (slot ^ (rowb & 7)) * 8;
  const int abase = (wm * (MI * 16) + lr) * 64;
  const int bbase = (wc * 64 + lr) * 64;
  const int s0 = ((lhi    ) ^ l7) * 8;
  const int s1 = ((lhi + 4) ^ l7) * 8;

  f32x4 acc[MI][4];
#pragma unroll
  for (int i = 0; i < MI; ++i)
#pragma unroll
    for (int j = 0; j < 4; ++j) acc[i][j] = (f32x4){0.f, 0.f, 0.f, 0.f};

#define GLL(SRC, DST) __builtin_amdgcn_global_load_lds(                      \
      (const __attribute__((address_space(1))) void*)(SRC),                  \
      (__attribute__((address_space(3))) void*)(DST), 16, 0, 0)

#define STAGE(KT, D) do {                                                    \
    const size_t ko_ = (size_t)(KT) * 64 + colel;                            \
    _Pragma("unroll")                                                        \
    for (int r_ = 0; r_ < MI; ++r_)                                          \
      GLL(Ab + (size_t)(r_ * 32 + rowb) * K + ko_,                           \
          &As[D][(r_ * 32 + rowb) * 64 + slot * 8]);                         \
    _Pragma("unroll")                                                        \
    for (int r_ = 0; r_ < 4; ++r_)                                           \
      GLL(Bb + (size_t)(r_ * 32 + rowb) * K + ko_,                           \
          &Bs[D][(r_ * 32 + rowb) * 64 + slot * 8]);                         \
  } while (0)

#define LD8(PTR, OFF) (*(const short8*)&(PTR)[OFF])
#define MFMA(AV, BV, C) __builtin_amdgcn_mfma_f32_16x16x32_bf16(AV, BV, C, 0, 0, 0)
#define SBAR __builtin_amdgcn_s_barrier()
#define SCHB __builtin_amdgcn_sched_barrier(0)

  STAGE(0, 0);
  STAGE(1, 1);

  int cur = 0;
  for (int kt = 0; kt < NT; ++kt) {
    if (kt + 1 < NT) {
      if constexpr (MI == 2) { asm volatile("s_waitcnt vmcnt(6)" ::: "memory"); }
      else                   { asm volatile("s_waitcnt vmcnt(8)" ::: "memory"); }
    } else                   { asm volatile("s_waitcnt vmcnt(0)" ::: "memory"); }
    SCHB; SBAR;
    const short* Ad = As[cur];
    const short* Bd = Bs[cur];
    short8 af0[MI], af1[MI], bf0v[4], bf1v[4];
    // k0 set (first MI+4 in lgkm queue)
#pragma unroll
    for (int i = 0; i < MI; ++i) af0[i] = LD8(Ad, abase + i * 1024 + s0);
#pragma unroll
    for (int n = 0; n < 4; ++n)  bf0v[n] = LD8(Bd, bbase + n * 1024 + s0);
    // k1 set (drains under MFMA k0)
#pragma unroll
    for (int i = 0; i < MI; ++i) af1[i] = LD8(Ad, abase + i * 1024 + s1);
#pragma unroll
    for (int n = 0; n < 4; ++n)  bf1v[n] = LD8(Bd, bbase + n * 1024 + s1);
    SCHB;
    if constexpr (MI == 2) { asm volatile("s_waitcnt lgkmcnt(6)" ::: "memory"); }
    else                   { asm volatile("s_waitcnt lgkmcnt(8)" ::: "memory"); }
    SCHB;
    __builtin_amdgcn_s_setprio(1);
#pragma unroll
    for (int i = 0; i < MI; ++i)
#pragma unroll
      for (int n = 0; n < 4; ++n) acc[i][n] = MFMA(af0[i], bf0v[n], acc[i][n]);
    __builtin_amdgcn_s_setprio(0);
    SCHB;
    asm volatile("s_waitcnt lgkmcnt(0)" ::: "memory");
    SCHB; SBAR;
    if (kt + 2 < NT) STAGE(kt + 2, cur);   // overlapped by MFMA k1
    SCHB;
    __builtin_amdgcn_s_setprio(1);
#pragma unroll
    for (int i = 0; i < MI; ++i)
#pragma unroll
      for (int n = 0; n < 4; ++n) acc[i][n] = MFMA(af1[i], bf1v[n], acc[i][n]);
    __builtin_amdgcn_s_setprio(0);
    SCHB;
    cur ^= 1;
  }

  // ---------------- epilogue ----------------
  float sv[4], qv[4];
#pragma unroll
  for (int ni = 0; ni < 4; ++ni) { sv[ni] = 0.f; qv[ni] = 0.f; }

#pragma unroll
  for (int mi = 0; mi < MI; ++mi) {
#pragma unroll
    for (int ni = 0; ni < 4; ++ni) {
#pragma unroll
      for (int j = 0; j < 4; ++j) {
        int r  = (int)row0 + wm * (MI * 16) + mi * 16 + lhi * 4 + j;
        int cc = (int)col0 + wc * 64 + ni * 16 + lr;
        float v = acc[mi][ni][j];
        if (EPI == 0) {
          sv[ni] += v; qv[ni] += v * v;
          int rr = r * 2 + bz;     // interleave even/odd k-rows
          ((short*)Cout)[((size_t)(cc >> 9) << 19) + (size_t)rr * 512 + (cc & 511)] = f2bf(v);
        } else if (EPI == 1) {
          ((short*)Cout)[(size_t)bz * 1048576 + (size_t)r * 1024 + cc] = f2bf(v > 0.f ? v : 0.f);
        } else {
          size_t idx = (size_t)bz * 524288 + (size_t)r * 1024 + cc;
          float g = 1.f / (1.f + __expf(-v));
          ((float*)Cout)[idx] = X[idx] * g;
        }
      }
    }
  }

  if (EPI == 0) {
    __syncthreads();
    float* redS = (float*)&As[0][0];       // [128 cols][8 contributors]
    float* redQ = redS + 1024;
    const int contrib = wm * 4 + lhi;
#pragma unroll
    for (int ni = 0; ni < 4; ++ni) {
      int ccl = wc * 64 + ni * 16 + lr;
      redS[ccl * 8 + contrib] = sv[ni];
      redQ[ccl * 8 + contrib] = qv[ni];
    }
    __syncthreads();
    if (tid < 128) {
      float S = 0.f, Q = 0.f;
#pragma unroll
      for (int i = 0; i < 8; ++i) { S += redS[tid * 8 + i]; Q += redQ[tid * 8 + i]; }
      float2 o; o.x = S; o.y = Q;
      P[(size_t)(bz * 8 + bx) * 16384 + col0 + tid] = o;
    }
  }
#undef MFMA
#undef LD8
#undef STAGE
#undef GLL
#undef SBAR
#undef SCHB
}

extern "C" void kernel_launch(void* const* d_in, const int* in_sizes, int n_in,
                              void* d_out, int out_size, void* d_ws, size_t ws_size,
                              hipStream_t stream) {
  const float* x    = (const float*)d_in[0];   // [32,512,1024]
  const float* w1   = (const float*)d_in[1];   // [1024,512]
  const float* w2   = (const float*)d_in[2];   // [512,1024]
  const float* ln_w = (const float*)d_in[3];   // [1024]
  const float* ln_b = (const float*)d_in[4];   // [1024]
  float* out = (float*)d_out;

  char* ws = (char*)d_ws;
  short* Deo    = (short*)(ws);                  //  1,048,576 B [2][512][512]
  short* w1_bf  = (short*)(ws + 1048576);        //  1,048,576 B
  short* w2_bf  = (short*)(ws + 2097152);        //  1,048,576 B
  short* freqT  = (short*)(ws + 3145728);        // 33,554,432 B [b][k][c]
  short* z1t    = (short*)(ws + 36700160);       // 67,108,864 B [b][p][o]
  short* eo     = z1t;                           // e/o alias z1t (dead by GEMM2)
  float2* part  = (float2*)(ws + 103809024);     //  2,097,152 B [16][16384]
  float2* musd  = (float2*)(ws + 105906176);     //    131,072 B [16384]
  // total ~106 MB

  prep_eo<<<dim3(8192), dim3(256), 0, stream>>>(x, eo);
  cast_kernel<<<dim3(512), dim3(256), 0, stream>>>(w1, w1_bf, 524288 / 4);
  cast_kernel<<<dim3(512), dim3(256), 0, stream>>>(w2, w2_bf, 524288 / 4);
  build_Deo<<<dim3(2048), dim3(256), 0, stream>>>(Deo);

  // GEMM1 (even/odd): C[k',(b,c)] = sum_n Deo[p][k',n]*eo[p][(b,c),n]
  // -> freqT rows 2k'+p, + LN partials. K=512, NT=8, grid 8bx*2p*128by.
  gemmT<0, 2><<<dim3(2048), dim3(256), 0, stream>>>(
      Deo, eo, (void*)freqT, nullptr, part, 512, 8, 262144, 8388608);

  // LN stats: fold 16 partials (2 parity x 8 bx) -> (mu, rstd) per (b,c)
  ln_stats<<<dim3(64), dim3(256), 0, stream>>>(part, musd);

  // LN apply: normalize freqT in place (streaming, vectorized)
  ln_apply<<<dim3(8192), dim3(256), 0, stream>>>(freqT, musd, ln_w, ln_b);

  // GEMM2: C[p,o] = sum_c Ht[b][p,c] * w1[o,c], relu -> z1t[b][p][o]
  gemmT<1, 2><<<dim3(4096), dim3(256), 0, stream>>>(
      freqT, w1_bf, (void*)z1t, nullptr, nullptr, 512, 8, 524288, 0);

  // GEMM3: C[o2,p] = sum_j w2[o2,j] * z1t[b][p,j]; out = x * sigmoid(C)
  gemmT<2, 2><<<dim3(2048), dim3(256), 0, stream>>>(
      w2_bf, z1t, (void*)out, x, nullptr, 1024, 16, 0, 1048576);
}